// Round 1
// baseline (568.869 us; speedup 1.0000x reference)
//
#include <hip/hip_runtime.h>
#include <math.h>

// Instant-NGP fused forward: hash-grid encode (L=16,F=2,T=2^19) + 3-layer MLP.
// One thread per point. MLP weights staged in LDS (broadcast reads).

constexpr int      LVLS   = 16;
constexpr uint32_t TSIZE  = 1u << 19;
constexpr uint32_t TMASK  = TSIZE - 1u;
constexpr uint32_t PRIME1 = 2654435761u;
constexpr uint32_t PRIME2 = 805459861u;

struct ResArr { float v[LVLS]; };  // res[l] - 1.0f, precomputed on host

__global__ __launch_bounds__(256)
void ingp_fused(const float* __restrict__ x,
                const float* __restrict__ table,
                const float* __restrict__ w1, const float* __restrict__ b1,
                const float* __restrict__ w2, const float* __restrict__ b2,
                const float* __restrict__ w3, const float* __restrict__ b3,
                float* __restrict__ out, int n, ResArr res)
{
    __shared__ float s_w1[32 * 64];
    __shared__ float s_w2[64 * 64];
    __shared__ float s_w3[64 * 3];
    __shared__ float s_b1[64];
    __shared__ float s_b2[64];
    __shared__ float s_b3[3];

    for (int t = threadIdx.x; t < 32 * 64; t += 256) s_w1[t] = w1[t];
    for (int t = threadIdx.x; t < 64 * 64; t += 256) s_w2[t] = w2[t];
    for (int t = threadIdx.x; t < 64 * 3;  t += 256) s_w3[t] = w3[t];
    if (threadIdx.x < 64) {
        s_b1[threadIdx.x] = b1[threadIdx.x];
        s_b2[threadIdx.x] = b2[threadIdx.x];
    }
    if (threadIdx.x < 3) s_b3[threadIdx.x] = b3[threadIdx.x];
    __syncthreads();

    const int i = blockIdx.x * 256 + threadIdx.x;
    if (i >= n) return;

    const float xx = x[3 * i + 0];
    const float xy = x[3 * i + 1];
    const float xz = x[3 * i + 2];

    float feat[32];
    #pragma unroll
    for (int l = 0; l < LVLS; ++l) {
        const float rm1 = res.v[l];
        const float px = xx * rm1, py = xy * rm1, pz = xz * rm1;
        const float fpx = floorf(px), fpy = floorf(py), fpz = floorf(pz);
        const float fx = px - fpx, fy = py - fpy, fz = pz - fpz;
        const uint32_t ix = (uint32_t)fpx;
        const uint32_t iy = (uint32_t)fpy;
        const uint32_t iz = (uint32_t)fpz;
        const uint32_t hy0 = iy * PRIME1, hy1 = (iy + 1u) * PRIME1;
        const uint32_t hz0 = iz * PRIME2, hz1 = (iz + 1u) * PRIME2;
        const float* tl = table + (size_t)l * (size_t)TSIZE * 2u;

        float a0 = 0.f, a1 = 0.f;
        #pragma unroll
        for (int c = 0; c < 8; ++c) {
            const int bi = (c >> 2) & 1, bj = (c >> 1) & 1, bk = c & 1;
            const uint32_t h =
                ((ix + (uint32_t)bi) ^ (bj ? hy1 : hy0) ^ (bk ? hz1 : hz0)) & TMASK;
            const float2 tv = *reinterpret_cast<const float2*>(tl + (size_t)h * 2u);
            const float w = (bi ? fx : 1.f - fx) *
                            (bj ? fy : 1.f - fy) *
                            (bk ? fz : 1.f - fz);
            a0 = fmaf(w, tv.x, a0);
            a1 = fmaf(w, tv.y, a1);
        }
        feat[2 * l + 0] = a0;
        feat[2 * l + 1] = a1;
    }

    // layer 1: [32] -> [64], relu
    float h1[64];
    #pragma unroll
    for (int j = 0; j < 64; ++j) h1[j] = s_b1[j];
    #pragma unroll
    for (int k = 0; k < 32; ++k) {
        const float fv = feat[k];
        #pragma unroll
        for (int j = 0; j < 64; ++j) h1[j] = fmaf(fv, s_w1[k * 64 + j], h1[j]);
    }
    #pragma unroll
    for (int j = 0; j < 64; ++j) h1[j] = fmaxf(h1[j], 0.f);

    // layer 2: [64] -> [64], relu
    float h2[64];
    #pragma unroll
    for (int j = 0; j < 64; ++j) h2[j] = s_b2[j];
    #pragma unroll
    for (int k = 0; k < 64; ++k) {
        const float hv = h1[k];
        #pragma unroll
        for (int j = 0; j < 64; ++j) h2[j] = fmaf(hv, s_w2[k * 64 + j], h2[j]);
    }
    #pragma unroll
    for (int j = 0; j < 64; ++j) h2[j] = fmaxf(h2[j], 0.f);

    // layer 3: [64] -> [3], sigmoid
    float o0 = s_b3[0], o1 = s_b3[1], o2 = s_b3[2];
    #pragma unroll
    for (int j = 0; j < 64; ++j) {
        const float hv = h2[j];
        o0 = fmaf(hv, s_w3[j * 3 + 0], o0);
        o1 = fmaf(hv, s_w3[j * 3 + 1], o1);
        o2 = fmaf(hv, s_w3[j * 3 + 2], o2);
    }
    out[3 * i + 0] = 1.f / (1.f + __expf(-o0));
    out[3 * i + 1] = 1.f / (1.f + __expf(-o1));
    out[3 * i + 2] = 1.f / (1.f + __expf(-o2));
}

extern "C" void kernel_launch(void* const* d_in, const int* in_sizes, int n_in,
                              void* d_out, int out_size, void* d_ws, size_t ws_size,
                              hipStream_t stream)
{
    const float* x     = (const float*)d_in[0];
    const float* table = (const float*)d_in[1];
    const float* w1    = (const float*)d_in[2];
    const float* b1    = (const float*)d_in[3];
    const float* w2    = (const float*)d_in[4];
    const float* b2    = (const float*)d_in[5];
    const float* w3    = (const float*)d_in[6];
    const float* b3    = (const float*)d_in[7];
    float* out = (float*)d_out;

    const int n = in_sizes[0] / 3;

    // res[l] = floor(16 * SCALE^l) computed in double from the f32-rounded SCALE,
    // then subtract 1 (reference uses pos = x * (res - 1)).
    ResArr res;
    const double S = (double)1.3819061f;
    double p = 1.0;
    for (int l = 0; l < LVLS; ++l) {
        res.v[l] = (float)floor(16.0 * p) - 1.0f;
        p *= S;
    }

    const int grid = (n + 255) / 256;
    ingp_fused<<<grid, 256, 0, stream>>>(x, table, w1, b1, w2, b2, w3, b3,
                                         out, n, res);
}

// Round 2
// 437.207 us; speedup vs baseline: 1.3011x; 1.3011x over previous
//
#include <hip/hip_runtime.h>
#include <hip/hip_fp16.h>
#include <math.h>

// Instant-NGP forward, split into:
//   A) hash-grid encode: one thread per (point, level), high occupancy to hide
//      gather latency; level-major grid so each level's 4MB table slab fits
//      the per-XCD L2 while that level is being processed.
//   B) MLP: one thread per point, weights staged in LDS.
// feat passed via d_ws as packed fp16 pairs, layout [L][N] (coalesced both ways).

constexpr int      LVLS   = 16;
constexpr uint32_t TSIZE  = 1u << 19;
constexpr uint32_t TMASK  = TSIZE - 1u;
constexpr uint32_t PRIME1 = 2654435761u;
constexpr uint32_t PRIME2 = 805459861u;

struct ResArr { float v[LVLS]; };  // res[l] - 1.0f, precomputed on host

// ---------------- Kernel A: encode ----------------
__global__ __launch_bounds__(256, 8)
void ingp_encode(const float* __restrict__ x,
                 const float* __restrict__ table,
                 __half2* __restrict__ feat16, int n, ResArr res)
{
    const int i = blockIdx.x * 256 + threadIdx.x;
    const int l = blockIdx.y;
    if (i >= n) return;

    const float xx = x[3 * i + 0];
    const float xy = x[3 * i + 1];
    const float xz = x[3 * i + 2];

    const float rm1 = res.v[l];
    const float px = xx * rm1, py = xy * rm1, pz = xz * rm1;
    const float fpx = floorf(px), fpy = floorf(py), fpz = floorf(pz);
    const float fx = px - fpx, fy = py - fpy, fz = pz - fpz;
    const uint32_t ix = (uint32_t)fpx;
    const uint32_t iy = (uint32_t)fpy;
    const uint32_t iz = (uint32_t)fpz;
    const uint32_t hy0 = iy * PRIME1, hy1 = (iy + 1u) * PRIME1;
    const uint32_t hz0 = iz * PRIME2, hz1 = (iz + 1u) * PRIME2;
    const float* tl = table + (size_t)l * (size_t)TSIZE * 2u;

    uint32_t hidx[8];
    #pragma unroll
    for (int c = 0; c < 8; ++c) {
        const uint32_t bi = (c >> 2) & 1, bj = (c >> 1) & 1, bk = c & 1;
        hidx[c] = ((ix + bi) ^ (bj ? hy1 : hy0) ^ (bk ? hz1 : hz0)) & TMASK;
    }
    float2 tv[8];
    #pragma unroll
    for (int c = 0; c < 8; ++c)
        tv[c] = *reinterpret_cast<const float2*>(tl + (size_t)hidx[c] * 2u);

    float a0 = 0.f, a1 = 0.f;
    #pragma unroll
    for (int c = 0; c < 8; ++c) {
        const int bi = (c >> 2) & 1, bj = (c >> 1) & 1, bk = c & 1;
        const float w = (bi ? fx : 1.f - fx) *
                        (bj ? fy : 1.f - fy) *
                        (bk ? fz : 1.f - fz);
        a0 = fmaf(w, tv[c].x, a0);
        a1 = fmaf(w, tv[c].y, a1);
    }
    feat16[(size_t)l * n + i] = __floats2half2_rn(a0, a1);
}

// ---------------- Kernel B: MLP ----------------
__global__ __launch_bounds__(256)
void ingp_mlp(const __half2* __restrict__ feat16,
              const float* __restrict__ w1, const float* __restrict__ b1,
              const float* __restrict__ w2, const float* __restrict__ b2,
              const float* __restrict__ w3, const float* __restrict__ b3,
              float* __restrict__ out, int n)
{
    __shared__ float s_w1[32 * 64];
    __shared__ float s_w2[64 * 64];
    __shared__ float s_w3[64 * 3];
    __shared__ float s_b1[64];
    __shared__ float s_b2[64];
    __shared__ float s_b3[3];

    for (int t = threadIdx.x; t < 32 * 64; t += 256) s_w1[t] = w1[t];
    for (int t = threadIdx.x; t < 64 * 64; t += 256) s_w2[t] = w2[t];
    for (int t = threadIdx.x; t < 64 * 3;  t += 256) s_w3[t] = w3[t];
    if (threadIdx.x < 64) {
        s_b1[threadIdx.x] = b1[threadIdx.x];
        s_b2[threadIdx.x] = b2[threadIdx.x];
    }
    if (threadIdx.x < 3) s_b3[threadIdx.x] = b3[threadIdx.x];
    __syncthreads();

    const int i = blockIdx.x * 256 + threadIdx.x;
    if (i >= n) return;

    float feat[32];
    #pragma unroll
    for (int l = 0; l < LVLS; ++l) {
        const float2 f = __half22float2(feat16[(size_t)l * n + i]);
        feat[2 * l + 0] = f.x;
        feat[2 * l + 1] = f.y;
    }

    float h1[64];
    #pragma unroll
    for (int j = 0; j < 64; ++j) h1[j] = s_b1[j];
    #pragma unroll
    for (int k = 0; k < 32; ++k) {
        const float fv = feat[k];
        #pragma unroll
        for (int j = 0; j < 64; ++j) h1[j] = fmaf(fv, s_w1[k * 64 + j], h1[j]);
    }
    #pragma unroll
    for (int j = 0; j < 64; ++j) h1[j] = fmaxf(h1[j], 0.f);

    float h2[64];
    #pragma unroll
    for (int j = 0; j < 64; ++j) h2[j] = s_b2[j];
    #pragma unroll
    for (int k = 0; k < 64; ++k) {
        const float hv = h1[k];
        #pragma unroll
        for (int j = 0; j < 64; ++j) h2[j] = fmaf(hv, s_w2[k * 64 + j], h2[j]);
    }
    #pragma unroll
    for (int j = 0; j < 64; ++j) h2[j] = fmaxf(h2[j], 0.f);

    float o0 = s_b3[0], o1 = s_b3[1], o2 = s_b3[2];
    #pragma unroll
    for (int j = 0; j < 64; ++j) {
        const float hv = h2[j];
        o0 = fmaf(hv, s_w3[j * 3 + 0], o0);
        o1 = fmaf(hv, s_w3[j * 3 + 1], o1);
        o2 = fmaf(hv, s_w3[j * 3 + 2], o2);
    }
    out[3 * i + 0] = 1.f / (1.f + __expf(-o0));
    out[3 * i + 1] = 1.f / (1.f + __expf(-o1));
    out[3 * i + 2] = 1.f / (1.f + __expf(-o2));
}

// ---------------- Fallback: original fused kernel (ws too small) ----------------
__global__ __launch_bounds__(256)
void ingp_fused(const float* __restrict__ x,
                const float* __restrict__ table,
                const float* __restrict__ w1, const float* __restrict__ b1,
                const float* __restrict__ w2, const float* __restrict__ b2,
                const float* __restrict__ w3, const float* __restrict__ b3,
                float* __restrict__ out, int n, ResArr res)
{
    __shared__ float s_w1[32 * 64];
    __shared__ float s_w2[64 * 64];
    __shared__ float s_w3[64 * 3];
    __shared__ float s_b1[64];
    __shared__ float s_b2[64];
    __shared__ float s_b3[3];
    for (int t = threadIdx.x; t < 32 * 64; t += 256) s_w1[t] = w1[t];
    for (int t = threadIdx.x; t < 64 * 64; t += 256) s_w2[t] = w2[t];
    for (int t = threadIdx.x; t < 64 * 3;  t += 256) s_w3[t] = w3[t];
    if (threadIdx.x < 64) { s_b1[threadIdx.x] = b1[threadIdx.x]; s_b2[threadIdx.x] = b2[threadIdx.x]; }
    if (threadIdx.x < 3) s_b3[threadIdx.x] = b3[threadIdx.x];
    __syncthreads();

    const int i = blockIdx.x * 256 + threadIdx.x;
    if (i >= n) return;
    const float xx = x[3 * i + 0], xy = x[3 * i + 1], xz = x[3 * i + 2];

    float feat[32];
    #pragma unroll
    for (int l = 0; l < LVLS; ++l) {
        const float rm1 = res.v[l];
        const float px = xx * rm1, py = xy * rm1, pz = xz * rm1;
        const float fpx = floorf(px), fpy = floorf(py), fpz = floorf(pz);
        const float fx = px - fpx, fy = py - fpy, fz = pz - fpz;
        const uint32_t ix = (uint32_t)fpx, iy = (uint32_t)fpy, iz = (uint32_t)fpz;
        const uint32_t hy0 = iy * PRIME1, hy1 = (iy + 1u) * PRIME1;
        const uint32_t hz0 = iz * PRIME2, hz1 = (iz + 1u) * PRIME2;
        const float* tl = table + (size_t)l * (size_t)TSIZE * 2u;
        float a0 = 0.f, a1 = 0.f;
        #pragma unroll
        for (int c = 0; c < 8; ++c) {
            const int bi = (c >> 2) & 1, bj = (c >> 1) & 1, bk = c & 1;
            const uint32_t h = ((ix + (uint32_t)bi) ^ (bj ? hy1 : hy0) ^ (bk ? hz1 : hz0)) & TMASK;
            const float2 tv = *reinterpret_cast<const float2*>(tl + (size_t)h * 2u);
            const float w = (bi ? fx : 1.f - fx) * (bj ? fy : 1.f - fy) * (bk ? fz : 1.f - fz);
            a0 = fmaf(w, tv.x, a0);
            a1 = fmaf(w, tv.y, a1);
        }
        feat[2 * l + 0] = a0;
        feat[2 * l + 1] = a1;
    }
    float h1[64];
    #pragma unroll
    for (int j = 0; j < 64; ++j) h1[j] = s_b1[j];
    #pragma unroll
    for (int k = 0; k < 32; ++k) {
        const float fv = feat[k];
        #pragma unroll
        for (int j = 0; j < 64; ++j) h1[j] = fmaf(fv, s_w1[k * 64 + j], h1[j]);
    }
    #pragma unroll
    for (int j = 0; j < 64; ++j) h1[j] = fmaxf(h1[j], 0.f);
    float h2[64];
    #pragma unroll
    for (int j = 0; j < 64; ++j) h2[j] = s_b2[j];
    #pragma unroll
    for (int k = 0; k < 64; ++k) {
        const float hv = h1[k];
        #pragma unroll
        for (int j = 0; j < 64; ++j) h2[j] = fmaf(hv, s_w2[k * 64 + j], h2[j]);
    }
    #pragma unroll
    for (int j = 0; j < 64; ++j) h2[j] = fmaxf(h2[j], 0.f);
    float o0 = s_b3[0], o1 = s_b3[1], o2 = s_b3[2];
    #pragma unroll
    for (int j = 0; j < 64; ++j) {
        const float hv = h2[j];
        o0 = fmaf(hv, s_w3[j * 3 + 0], o0);
        o1 = fmaf(hv, s_w3[j * 3 + 1], o1);
        o2 = fmaf(hv, s_w3[j * 3 + 2], o2);
    }
    out[3 * i + 0] = 1.f / (1.f + __expf(-o0));
    out[3 * i + 1] = 1.f / (1.f + __expf(-o1));
    out[3 * i + 2] = 1.f / (1.f + __expf(-o2));
}

extern "C" void kernel_launch(void* const* d_in, const int* in_sizes, int n_in,
                              void* d_out, int out_size, void* d_ws, size_t ws_size,
                              hipStream_t stream)
{
    const float* x     = (const float*)d_in[0];
    const float* table = (const float*)d_in[1];
    const float* w1    = (const float*)d_in[2];
    const float* b1    = (const float*)d_in[3];
    const float* w2    = (const float*)d_in[4];
    const float* b2    = (const float*)d_in[5];
    const float* w3    = (const float*)d_in[6];
    const float* b3    = (const float*)d_in[7];
    float* out = (float*)d_out;

    const int n = in_sizes[0] / 3;

    ResArr res;
    const double S = (double)1.3819061f;
    double p = 1.0;
    for (int l = 0; l < LVLS; ++l) {
        res.v[l] = (float)floor(16.0 * p) - 1.0f;
        p *= S;
    }

    const int gb = (n + 255) / 256;
    const size_t need = (size_t)LVLS * (size_t)n * sizeof(__half2);  // 32 MB

    if (ws_size >= need) {
        dim3 gridA(gb, LVLS);
        ingp_encode<<<gridA, 256, 0, stream>>>(x, table, (__half2*)d_ws, n, res);
        ingp_mlp<<<gb, 256, 0, stream>>>((const __half2*)d_ws,
                                         w1, b1, w2, b2, w3, b3, out, n);
    } else {
        ingp_fused<<<gb, 256, 0, stream>>>(x, table, w1, b1, w2, b2, w3, b3,
                                           out, n, res);
    }
}

// Round 3
// 269.148 us; speedup vs baseline: 2.1136x; 1.6244x over previous
//
#include <hip/hip_runtime.h>
#include <hip/hip_fp16.h>
#include <math.h>

// Instant-NGP forward:
//   prep:   f32 weights -> bf16 transposed (B^T, contiguous-K) tables in ws
//   encode: one thread per (point, level); bf16 feature pairs to ws [L][N]
//   mlp:    MFMA bf16 16x16x32; 4 waves/block, 64 points/wave;
//           inter-layer transpose via padded per-wave LDS tile.

constexpr int      LVLS   = 16;
constexpr uint32_t TSIZE  = 1u << 19;
constexpr uint32_t TMASK  = TSIZE - 1u;
constexpr uint32_t PRIME1 = 2654435761u;
constexpr uint32_t PRIME2 = 805459861u;

struct ResArr { float v[LVLS]; };  // res[l] - 1.0f

typedef __attribute__((ext_vector_type(8))) short short8v;  // 8 bf16 (4 VGPRs)
typedef __attribute__((ext_vector_type(4))) float float4v;  // MFMA 16x16 acc

__device__ inline ushort f2bf(float f) {          // RNE f32 -> bf16
    uint u = __float_as_uint(f);
    u += 0x7fffu + ((u >> 16) & 1u);
    return (ushort)(u >> 16);
}

// ---------------- prep: weight transpose + bf16 cast ----------------
__global__ __launch_bounds__(256)
void ingp_prep(const float* __restrict__ w1, const float* __restrict__ w2,
               const float* __restrict__ w3,
               ushort* __restrict__ w1t, ushort* __restrict__ w2t,
               ushort* __restrict__ w3t)
{
    const int t = blockIdx.x * 256 + threadIdx.x;
    if (t < 2048) {                       // w1t[n*32+k] = w1[k*64+n]
        const int nn = t >> 5, k = t & 31;
        w1t[t] = f2bf(w1[k * 64 + nn]);
    } else if (t < 2048 + 4096) {         // w2t[n*64+k] = w2[k*64+n]
        const int q = t - 2048;
        const int nn = q >> 6, k = q & 63;
        w2t[q] = f2bf(w2[k * 64 + nn]);
    } else if (t < 2048 + 4096 + 1024) {  // w3t padded to [16][64]
        const int q = t - 6144;
        const int nn = q >> 6, k = q & 63;
        w3t[q] = (nn < 3) ? f2bf(w3[k * 3 + nn]) : (ushort)0;
    }
}

// ---------------- Kernel A: encode ----------------
__global__ __launch_bounds__(256, 8)
void ingp_encode(const float* __restrict__ x,
                 const float* __restrict__ table,
                 uint* __restrict__ feat, int n, ResArr res)
{
    const int i = blockIdx.x * 256 + threadIdx.x;
    const int l = blockIdx.y;
    if (i >= n) return;

    const float xx = x[3 * i + 0];
    const float xy = x[3 * i + 1];
    const float xz = x[3 * i + 2];

    const float rm1 = res.v[l];
    const float px = xx * rm1, py = xy * rm1, pz = xz * rm1;
    const float fpx = floorf(px), fpy = floorf(py), fpz = floorf(pz);
    const float fx = px - fpx, fy = py - fpy, fz = pz - fpz;
    const uint32_t ix = (uint32_t)fpx;
    const uint32_t iy = (uint32_t)fpy;
    const uint32_t iz = (uint32_t)fpz;
    const uint32_t hy0 = iy * PRIME1, hy1 = (iy + 1u) * PRIME1;
    const uint32_t hz0 = iz * PRIME2, hz1 = (iz + 1u) * PRIME2;
    const float* tl = table + (size_t)l * (size_t)TSIZE * 2u;

    uint32_t hidx[8];
    #pragma unroll
    for (int c = 0; c < 8; ++c) {
        const uint32_t bi = (c >> 2) & 1, bj = (c >> 1) & 1, bk = c & 1;
        hidx[c] = ((ix + bi) ^ (bj ? hy1 : hy0) ^ (bk ? hz1 : hz0)) & TMASK;
    }
    float2 tv[8];
    #pragma unroll
    for (int c = 0; c < 8; ++c)
        tv[c] = *reinterpret_cast<const float2*>(tl + (size_t)hidx[c] * 2u);

    float a0 = 0.f, a1 = 0.f;
    #pragma unroll
    for (int c = 0; c < 8; ++c) {
        const int bi = (c >> 2) & 1, bj = (c >> 1) & 1, bk = c & 1;
        const float w = (bi ? fx : 1.f - fx) *
                        (bj ? fy : 1.f - fy) *
                        (bk ? fz : 1.f - fz);
        a0 = fmaf(w, tv[c].x, a0);
        a1 = fmaf(w, tv[c].y, a1);
    }
    feat[(size_t)l * n + i] = (uint)f2bf(a0) | ((uint)f2bf(a1) << 16);
}

// ---------------- Kernel B: MFMA MLP ----------------
__global__ __launch_bounds__(256)
void ingp_mlp_mfma(const uint* __restrict__ feat,
                   const ushort* __restrict__ w1t,
                   const ushort* __restrict__ w2t,
                   const ushort* __restrict__ w3t,
                   const float* __restrict__ b1,
                   const float* __restrict__ b2,
                   const float* __restrict__ b3,
                   float* __restrict__ out, int n)
{
    __shared__ ushort s_h[4][64][72];   // per-wave transpose tile, padded (+8)
    const int tid = threadIdx.x;
    const int wv = tid >> 6;
    const int ln = tid & 63;
    const int lm = ln & 15;             // row (A) / col (B,D)
    const int lk = ln >> 4;             // k-group
    const int base = blockIdx.x * 256 + wv * 64;

    // ---- layer 1: [64x32] @ [32x64] ----
    short8v a1[4];
    #pragma unroll
    for (int mt = 0; mt < 4; ++mt) {
        int pt = base + mt * 16 + lm;
        pt = pt < n ? pt : (n - 1);
        union { uint u[4]; short8v v; } c;
        #pragma unroll
        for (int j = 0; j < 4; ++j)
            c.u[j] = feat[(size_t)(lk * 4 + j) * (size_t)n + pt];
        a1[mt] = c.v;
    }

    float4v acc[4][4];
    #pragma unroll
    for (int nt = 0; nt < 4; ++nt) {
        const float bv = b1[nt * 16 + lm];
        #pragma unroll
        for (int mt = 0; mt < 4; ++mt)
            acc[mt][nt] = (float4v){bv, bv, bv, bv};
    }
    #pragma unroll
    for (int nt = 0; nt < 4; ++nt) {
        const short8v bfr = *(const short8v*)(w1t + (nt * 16 + lm) * 32 + lk * 8);
        #pragma unroll
        for (int mt = 0; mt < 4; ++mt)
            acc[mt][nt] = __builtin_amdgcn_mfma_f32_16x16x32_bf16(
                a1[mt], bfr, acc[mt][nt], 0, 0, 0);
    }
    // relu -> bf16 -> LDS (D layout: row = lk*4+r, col = lm)
    #pragma unroll
    for (int mt = 0; mt < 4; ++mt)
        #pragma unroll
        for (int nt = 0; nt < 4; ++nt)
            #pragma unroll
            for (int r = 0; r < 4; ++r)
                s_h[wv][mt * 16 + lk * 4 + r][nt * 16 + lm] =
                    f2bf(fmaxf(acc[mt][nt][r], 0.f));
    __syncthreads();

    // ---- layer 2: [64x64] @ [64x64] ----
    float4v acc2[4][4];
    #pragma unroll
    for (int nt = 0; nt < 4; ++nt) {
        const float bv = b2[nt * 16 + lm];
        #pragma unroll
        for (int mt = 0; mt < 4; ++mt)
            acc2[mt][nt] = (float4v){bv, bv, bv, bv};
    }
    #pragma unroll
    for (int ks = 0; ks < 2; ++ks) {
        short8v a2[4];
        #pragma unroll
        for (int mt = 0; mt < 4; ++mt)
            a2[mt] = *(const short8v*)&s_h[wv][mt * 16 + lm][ks * 32 + lk * 8];
        #pragma unroll
        for (int nt = 0; nt < 4; ++nt) {
            const short8v bfr =
                *(const short8v*)(w2t + (nt * 16 + lm) * 64 + ks * 32 + lk * 8);
            #pragma unroll
            for (int mt = 0; mt < 4; ++mt)
                acc2[mt][nt] = __builtin_amdgcn_mfma_f32_16x16x32_bf16(
                    a2[mt], bfr, acc2[mt][nt], 0, 0, 0);
        }
    }
    __syncthreads();
    #pragma unroll
    for (int mt = 0; mt < 4; ++mt)
        #pragma unroll
        for (int nt = 0; nt < 4; ++nt)
            #pragma unroll
            for (int r = 0; r < 4; ++r)
                s_h[wv][mt * 16 + lk * 4 + r][nt * 16 + lm] =
                    f2bf(fmaxf(acc2[mt][nt][r], 0.f));
    __syncthreads();

    // ---- layer 3: [64x64] @ [64x16(pad of 3)] ----
    float4v acc3[4];
    const float bv3 = (lm < 3) ? b3[lm] : 0.f;
    #pragma unroll
    for (int mt = 0; mt < 4; ++mt)
        acc3[mt] = (float4v){bv3, bv3, bv3, bv3};
    #pragma unroll
    for (int ks = 0; ks < 2; ++ks) {
        const short8v bfr = *(const short8v*)(w3t + lm * 64 + ks * 32 + lk * 8);
        #pragma unroll
        for (int mt = 0; mt < 4; ++mt) {
            const short8v a3 =
                *(const short8v*)&s_h[wv][mt * 16 + lm][ks * 32 + lk * 8];
            acc3[mt] = __builtin_amdgcn_mfma_f32_16x16x32_bf16(
                a3, bfr, acc3[mt], 0, 0, 0);
        }
    }
    if (lm < 3) {
        #pragma unroll
        for (int mt = 0; mt < 4; ++mt)
            #pragma unroll
            for (int r = 0; r < 4; ++r) {
                const int pt = base + mt * 16 + lk * 4 + r;
                if (pt < n)
                    out[pt * 3 + lm] = 1.f / (1.f + __expf(-acc3[mt][r]));
            }
    }
}

// ---------------- fallback: f32 MLP (round-2 path) ----------------
__global__ __launch_bounds__(256)
void ingp_mlp(const __half2* __restrict__ feat16,
              const float* __restrict__ w1, const float* __restrict__ b1,
              const float* __restrict__ w2, const float* __restrict__ b2,
              const float* __restrict__ w3, const float* __restrict__ b3,
              float* __restrict__ out, int n)
{
    __shared__ float s_w1[32 * 64];
    __shared__ float s_w2[64 * 64];
    __shared__ float s_w3[64 * 3];
    __shared__ float s_b1[64];
    __shared__ float s_b2[64];
    __shared__ float s_b3[3];
    for (int t = threadIdx.x; t < 32 * 64; t += 256) s_w1[t] = w1[t];
    for (int t = threadIdx.x; t < 64 * 64; t += 256) s_w2[t] = w2[t];
    for (int t = threadIdx.x; t < 64 * 3;  t += 256) s_w3[t] = w3[t];
    if (threadIdx.x < 64) { s_b1[threadIdx.x] = b1[threadIdx.x]; s_b2[threadIdx.x] = b2[threadIdx.x]; }
    if (threadIdx.x < 3) s_b3[threadIdx.x] = b3[threadIdx.x];
    __syncthreads();
    const int i = blockIdx.x * 256 + threadIdx.x;
    if (i >= n) return;
    float feat[32];
    #pragma unroll
    for (int l = 0; l < LVLS; ++l) {
        const float2 f = __half22float2(feat16[(size_t)l * n + i]);
        feat[2 * l + 0] = f.x;
        feat[2 * l + 1] = f.y;
    }
    float h1[64];
    #pragma unroll
    for (int j = 0; j < 64; ++j) h1[j] = s_b1[j];
    #pragma unroll
    for (int k = 0; k < 32; ++k) {
        const float fv = feat[k];
        #pragma unroll
        for (int j = 0; j < 64; ++j) h1[j] = fmaf(fv, s_w1[k * 64 + j], h1[j]);
    }
    #pragma unroll
    for (int j = 0; j < 64; ++j) h1[j] = fmaxf(h1[j], 0.f);
    float h2[64];
    #pragma unroll
    for (int j = 0; j < 64; ++j) h2[j] = s_b2[j];
    #pragma unroll
    for (int k = 0; k < 64; ++k) {
        const float hv = h1[k];
        #pragma unroll
        for (int j = 0; j < 64; ++j) h2[j] = fmaf(hv, s_w2[k * 64 + j], h2[j]);
    }
    #pragma unroll
    for (int j = 0; j < 64; ++j) h2[j] = fmaxf(h2[j], 0.f);
    float o0 = s_b3[0], o1 = s_b3[1], o2 = s_b3[2];
    #pragma unroll
    for (int j = 0; j < 64; ++j) {
        const float hv = h2[j];
        o0 = fmaf(hv, s_w3[j * 3 + 0], o0);
        o1 = fmaf(hv, s_w3[j * 3 + 1], o1);
        o2 = fmaf(hv, s_w3[j * 3 + 2], o2);
    }
    out[3 * i + 0] = 1.f / (1.f + __expf(-o0));
    out[3 * i + 1] = 1.f / (1.f + __expf(-o1));
    out[3 * i + 2] = 1.f / (1.f + __expf(-o2));
}

// encode variant for the fp16 fallback path
__global__ __launch_bounds__(256, 8)
void ingp_encode_h2(const float* __restrict__ x,
                    const float* __restrict__ table,
                    __half2* __restrict__ feat16, int n, ResArr res)
{
    const int i = blockIdx.x * 256 + threadIdx.x;
    const int l = blockIdx.y;
    if (i >= n) return;
    const float xx = x[3 * i + 0], xy = x[3 * i + 1], xz = x[3 * i + 2];
    const float rm1 = res.v[l];
    const float px = xx * rm1, py = xy * rm1, pz = xz * rm1;
    const float fpx = floorf(px), fpy = floorf(py), fpz = floorf(pz);
    const float fx = px - fpx, fy = py - fpy, fz = pz - fpz;
    const uint32_t ix = (uint32_t)fpx, iy = (uint32_t)fpy, iz = (uint32_t)fpz;
    const uint32_t hy0 = iy * PRIME1, hy1 = (iy + 1u) * PRIME1;
    const uint32_t hz0 = iz * PRIME2, hz1 = (iz + 1u) * PRIME2;
    const float* tl = table + (size_t)l * (size_t)TSIZE * 2u;
    float a0 = 0.f, a1 = 0.f;
    #pragma unroll
    for (int c = 0; c < 8; ++c) {
        const int bi = (c >> 2) & 1, bj = (c >> 1) & 1, bk = c & 1;
        const uint32_t h = ((ix + (uint32_t)bi) ^ (bj ? hy1 : hy0) ^ (bk ? hz1 : hz0)) & TMASK;
        const float2 tv = *reinterpret_cast<const float2*>(tl + (size_t)h * 2u);
        const float w = (bi ? fx : 1.f - fx) * (bj ? fy : 1.f - fy) * (bk ? fz : 1.f - fz);
        a0 = fmaf(w, tv.x, a0);
        a1 = fmaf(w, tv.y, a1);
    }
    feat16[(size_t)l * n + i] = __floats2half2_rn(a0, a1);
}

extern "C" void kernel_launch(void* const* d_in, const int* in_sizes, int n_in,
                              void* d_out, int out_size, void* d_ws, size_t ws_size,
                              hipStream_t stream)
{
    const float* x     = (const float*)d_in[0];
    const float* table = (const float*)d_in[1];
    const float* w1    = (const float*)d_in[2];
    const float* b1    = (const float*)d_in[3];
    const float* w2    = (const float*)d_in[4];
    const float* b2    = (const float*)d_in[5];
    const float* w3    = (const float*)d_in[6];
    const float* b3    = (const float*)d_in[7];
    float* out = (float*)d_out;

    const int n = in_sizes[0] / 3;

    ResArr res;
    const double S = (double)1.3819061f;
    double p = 1.0;
    for (int l = 0; l < LVLS; ++l) {
        res.v[l] = (float)floor(16.0 * p) - 1.0f;
        p *= S;
    }

    const int gb = (n + 255) / 256;
    const size_t feat_bytes = (size_t)LVLS * (size_t)n * 4u;        // 32 MB
    const size_t need_mfma  = 16384 + feat_bytes;

    if (ws_size >= need_mfma) {
        ushort* w1t = (ushort*)d_ws;           // 2048 elems
        ushort* w2t = w1t + 2048;              // 4096 elems
        ushort* w3t = w2t + 4096;              // 1024 elems
        uint*   feat = (uint*)((char*)d_ws + 16384);
        ingp_prep<<<28, 256, 0, stream>>>(w1, w2, w3, w1t, w2t, w3t);
        dim3 gridA(gb, LVLS);
        ingp_encode<<<gridA, 256, 0, stream>>>(x, table, feat, n, res);
        ingp_mlp_mfma<<<gb, 256, 0, stream>>>(feat, w1t, w2t, w3t,
                                              b1, b2, b3, out, n);
    } else {
        dim3 gridA(gb, LVLS);
        ingp_encode_h2<<<gridA, 256, 0, stream>>>(x, table, (__half2*)d_ws, n, res);
        ingp_mlp<<<gb, 256, 0, stream>>>((const __half2*)d_ws,
                                         w1, b1, w2, b2, w3, b3, out, n);
    }
}

// Round 4
// 201.815 us; speedup vs baseline: 2.8188x; 1.3336x over previous
//
#include <hip/hip_runtime.h>
#include <hip/hip_fp16.h>
#include <math.h>

// Instant-NGP forward:
//   prep:   f32 weights -> bf16 transposed (B^T, contiguous-K) tables in ws
//   encode: one thread per (point, level); exploits dim0 hash prime == 1:
//           when ix is even, corners (0,bj,bk) and (1,bj,bk) are ADJACENT table
//           rows in one aligned 16B block -> single float4 load (8 -> 4 loads).
//   mlp:    MFMA bf16 16x16x32; 4 waves/block, 64 points/wave.

constexpr int      LVLS   = 16;
constexpr uint32_t TSIZE  = 1u << 19;
constexpr uint32_t TMASK  = TSIZE - 1u;
constexpr uint32_t PRIME1 = 2654435761u;
constexpr uint32_t PRIME2 = 805459861u;

struct ResArr { float v[LVLS]; };  // res[l] - 1.0f

typedef __attribute__((ext_vector_type(8))) short short8v;  // 8 bf16 (4 VGPRs)
typedef __attribute__((ext_vector_type(4))) float float4v;  // MFMA 16x16 acc

__device__ inline ushort f2bf(float f) {          // RNE f32 -> bf16
    uint u = __float_as_uint(f);
    u += 0x7fffu + ((u >> 16) & 1u);
    return (ushort)(u >> 16);
}

// ---------------- prep: weight transpose + bf16 cast ----------------
__global__ __launch_bounds__(256)
void ingp_prep(const float* __restrict__ w1, const float* __restrict__ w2,
               const float* __restrict__ w3,
               ushort* __restrict__ w1t, ushort* __restrict__ w2t,
               ushort* __restrict__ w3t)
{
    const int t = blockIdx.x * 256 + threadIdx.x;
    if (t < 2048) {                       // w1t[n*32+k] = w1[k*64+n]
        const int nn = t >> 5, k = t & 31;
        w1t[t] = f2bf(w1[k * 64 + nn]);
    } else if (t < 2048 + 4096) {         // w2t[n*64+k] = w2[k*64+n]
        const int q = t - 2048;
        const int nn = q >> 6, k = q & 63;
        w2t[q] = f2bf(w2[k * 64 + nn]);
    } else if (t < 2048 + 4096 + 1024) {  // w3t padded to [16][64]
        const int q = t - 6144;
        const int nn = q >> 6, k = q & 63;
        w3t[q] = (nn < 3) ? f2bf(w3[k * 3 + nn]) : (ushort)0;
    }
}

// ---------------- Kernel A: encode (paired-corner loads) ----------------
__global__ __launch_bounds__(256, 8)
void ingp_encode(const float* __restrict__ x,
                 const float* __restrict__ table,
                 uint* __restrict__ feat, int n, ResArr res)
{
    const int i = blockIdx.x * 256 + threadIdx.x;
    const int l = blockIdx.y;
    if (i >= n) return;

    const float xx = x[3 * i + 0];
    const float xy = x[3 * i + 1];
    const float xz = x[3 * i + 2];

    const float rm1 = res.v[l];
    const float px = xx * rm1, py = xy * rm1, pz = xz * rm1;
    const float fpx = floorf(px), fpy = floorf(py), fpz = floorf(pz);
    const float fx = px - fpx, fy = py - fpy, fz = pz - fpz;
    const uint32_t ix = (uint32_t)fpx;
    const uint32_t iy = (uint32_t)fpy;
    const uint32_t iz = (uint32_t)fpz;
    const uint32_t hy0 = iy * PRIME1, hy1 = (iy + 1u) * PRIME1;
    const uint32_t hz0 = iz * PRIME2, hz1 = (iz + 1u) * PRIME2;
    const float* tl = table + (size_t)l * (size_t)TSIZE * 2u;

    // per (bj,bk) pair: bi=0 index; bi=1 index = ((ix+1) ^ hyz) & TMASK
    uint32_t idx0[4], idx1[4];
    #pragma unroll
    for (int p = 0; p < 4; ++p) {
        const uint32_t bj = (p >> 1) & 1, bk = p & 1;
        const uint32_t hyz = (bj ? hy1 : hy0) ^ (bk ? hz1 : hz0);
        idx0[p] = (ix ^ hyz) & TMASK;
        idx1[p] = ((ix + 1u) ^ hyz) & TMASK;
    }

    float2 c0[4], c1[4];
    if ((ix & 1u) == 0u) {
        // even ix: idx1 == idx0^1 -> both corners in one aligned 16B block
        #pragma unroll
        for (int p = 0; p < 4; ++p) {
            const uint32_t base = idx0[p] & ~1u;
            const float4 q = *reinterpret_cast<const float4*>(tl + (size_t)base * 2u);
            if (idx0[p] & 1u) {
                c0[p] = make_float2(q.z, q.w);
                c1[p] = make_float2(q.x, q.y);
            } else {
                c0[p] = make_float2(q.x, q.y);
                c1[p] = make_float2(q.z, q.w);
            }
        }
    } else {
        #pragma unroll
        for (int p = 0; p < 4; ++p) {
            c0[p] = *reinterpret_cast<const float2*>(tl + (size_t)idx0[p] * 2u);
            c1[p] = *reinterpret_cast<const float2*>(tl + (size_t)idx1[p] * 2u);
        }
    }

    const float gx0 = 1.f - fx, gx1 = fx;
    float a0 = 0.f, a1 = 0.f;
    #pragma unroll
    for (int p = 0; p < 4; ++p) {
        const int bj = (p >> 1) & 1, bk = p & 1;
        const float wyz = (bj ? fy : 1.f - fy) * (bk ? fz : 1.f - fz);
        const float w0 = wyz * gx0, w1 = wyz * gx1;
        a0 = fmaf(w0, c0[p].x, a0);
        a1 = fmaf(w0, c0[p].y, a1);
        a0 = fmaf(w1, c1[p].x, a0);
        a1 = fmaf(w1, c1[p].y, a1);
    }
    feat[(size_t)l * n + i] = (uint)f2bf(a0) | ((uint)f2bf(a1) << 16);
}

// ---------------- Kernel B: MFMA MLP ----------------
__global__ __launch_bounds__(256)
void ingp_mlp_mfma(const uint* __restrict__ feat,
                   const ushort* __restrict__ w1t,
                   const ushort* __restrict__ w2t,
                   const ushort* __restrict__ w3t,
                   const float* __restrict__ b1,
                   const float* __restrict__ b2,
                   const float* __restrict__ b3,
                   float* __restrict__ out, int n)
{
    __shared__ ushort s_h[4][64][72];   // per-wave transpose tile, padded (+8)
    const int tid = threadIdx.x;
    const int wv = tid >> 6;
    const int ln = tid & 63;
    const int lm = ln & 15;             // row (A) / col (B,D)
    const int lk = ln >> 4;             // k-group
    const int base = blockIdx.x * 256 + wv * 64;

    // ---- layer 1: [64x32] @ [32x64] ----
    short8v a1[4];
    #pragma unroll
    for (int mt = 0; mt < 4; ++mt) {
        int pt = base + mt * 16 + lm;
        pt = pt < n ? pt : (n - 1);
        union { uint u[4]; short8v v; } c;
        #pragma unroll
        for (int j = 0; j < 4; ++j)
            c.u[j] = feat[(size_t)(lk * 4 + j) * (size_t)n + pt];
        a1[mt] = c.v;
    }

    float4v acc[4][4];
    #pragma unroll
    for (int nt = 0; nt < 4; ++nt) {
        const float bv = b1[nt * 16 + lm];
        #pragma unroll
        for (int mt = 0; mt < 4; ++mt)
            acc[mt][nt] = (float4v){bv, bv, bv, bv};
    }
    #pragma unroll
    for (int nt = 0; nt < 4; ++nt) {
        const short8v bfr = *(const short8v*)(w1t + (nt * 16 + lm) * 32 + lk * 8);
        #pragma unroll
        for (int mt = 0; mt < 4; ++mt)
            acc[mt][nt] = __builtin_amdgcn_mfma_f32_16x16x32_bf16(
                a1[mt], bfr, acc[mt][nt], 0, 0, 0);
    }
    // relu -> bf16 -> LDS (D layout: row = lk*4+r, col = lm)
    #pragma unroll
    for (int mt = 0; mt < 4; ++mt)
        #pragma unroll
        for (int nt = 0; nt < 4; ++nt)
            #pragma unroll
            for (int r = 0; r < 4; ++r)
                s_h[wv][mt * 16 + lk * 4 + r][nt * 16 + lm] =
                    f2bf(fmaxf(acc[mt][nt][r], 0.f));
    __syncthreads();

    // ---- layer 2: [64x64] @ [64x64] ----
    float4v acc2[4][4];
    #pragma unroll
    for (int nt = 0; nt < 4; ++nt) {
        const float bv = b2[nt * 16 + lm];
        #pragma unroll
        for (int mt = 0; mt < 4; ++mt)
            acc2[mt][nt] = (float4v){bv, bv, bv, bv};
    }
    #pragma unroll
    for (int ks = 0; ks < 2; ++ks) {
        short8v a2[4];
        #pragma unroll
        for (int mt = 0; mt < 4; ++mt)
            a2[mt] = *(const short8v*)&s_h[wv][mt * 16 + lm][ks * 32 + lk * 8];
        #pragma unroll
        for (int nt = 0; nt < 4; ++nt) {
            const short8v bfr =
                *(const short8v*)(w2t + (nt * 16 + lm) * 64 + ks * 32 + lk * 8);
            #pragma unroll
            for (int mt = 0; mt < 4; ++mt)
                acc2[mt][nt] = __builtin_amdgcn_mfma_f32_16x16x32_bf16(
                    a2[mt], bfr, acc2[mt][nt], 0, 0, 0);
        }
    }
    __syncthreads();
    #pragma unroll
    for (int mt = 0; mt < 4; ++mt)
        #pragma unroll
        for (int nt = 0; nt < 4; ++nt)
            #pragma unroll
            for (int r = 0; r < 4; ++r)
                s_h[wv][mt * 16 + lk * 4 + r][nt * 16 + lm] =
                    f2bf(fmaxf(acc2[mt][nt][r], 0.f));
    __syncthreads();

    // ---- layer 3: [64x64] @ [64x16(pad of 3)] ----
    float4v acc3[4];
    const float bv3 = (lm < 3) ? b3[lm] : 0.f;
    #pragma unroll
    for (int mt = 0; mt < 4; ++mt)
        acc3[mt] = (float4v){bv3, bv3, bv3, bv3};
    #pragma unroll
    for (int ks = 0; ks < 2; ++ks) {
        const short8v bfr = *(const short8v*)(w3t + lm * 64 + ks * 32 + lk * 8);
        #pragma unroll
        for (int mt = 0; mt < 4; ++mt) {
            const short8v a3 =
                *(const short8v*)&s_h[wv][mt * 16 + lm][ks * 32 + lk * 8];
            acc3[mt] = __builtin_amdgcn_mfma_f32_16x16x32_bf16(
                a3, bfr, acc3[mt], 0, 0, 0);
        }
    }
    if (lm < 3) {
        #pragma unroll
        for (int mt = 0; mt < 4; ++mt)
            #pragma unroll
            for (int r = 0; r < 4; ++r) {
                const int pt = base + mt * 16 + lk * 4 + r;
                if (pt < n)
                    out[pt * 3 + lm] = 1.f / (1.f + __expf(-acc3[mt][r]));
            }
    }
}

// ---------------- fallback: f32 MLP (round-2 path) ----------------
__global__ __launch_bounds__(256)
void ingp_mlp(const __half2* __restrict__ feat16,
              const float* __restrict__ w1, const float* __restrict__ b1,
              const float* __restrict__ w2, const float* __restrict__ b2,
              const float* __restrict__ w3, const float* __restrict__ b3,
              float* __restrict__ out, int n)
{
    __shared__ float s_w1[32 * 64];
    __shared__ float s_w2[64 * 64];
    __shared__ float s_w3[64 * 3];
    __shared__ float s_b1[64];
    __shared__ float s_b2[64];
    __shared__ float s_b3[3];
    for (int t = threadIdx.x; t < 32 * 64; t += 256) s_w1[t] = w1[t];
    for (int t = threadIdx.x; t < 64 * 64; t += 256) s_w2[t] = w2[t];
    for (int t = threadIdx.x; t < 64 * 3;  t += 256) s_w3[t] = w3[t];
    if (threadIdx.x < 64) { s_b1[threadIdx.x] = b1[threadIdx.x]; s_b2[threadIdx.x] = b2[threadIdx.x]; }
    if (threadIdx.x < 3) s_b3[threadIdx.x] = b3[threadIdx.x];
    __syncthreads();
    const int i = blockIdx.x * 256 + threadIdx.x;
    if (i >= n) return;
    float feat[32];
    #pragma unroll
    for (int l = 0; l < LVLS; ++l) {
        const float2 f = __half22float2(feat16[(size_t)l * n + i]);
        feat[2 * l + 0] = f.x;
        feat[2 * l + 1] = f.y;
    }
    float h1[64];
    #pragma unroll
    for (int j = 0; j < 64; ++j) h1[j] = s_b1[j];
    #pragma unroll
    for (int k = 0; k < 32; ++k) {
        const float fv = feat[k];
        #pragma unroll
        for (int j = 0; j < 64; ++j) h1[j] = fmaf(fv, s_w1[k * 64 + j], h1[j]);
    }
    #pragma unroll
    for (int j = 0; j < 64; ++j) h1[j] = fmaxf(h1[j], 0.f);
    float h2[64];
    #pragma unroll
    for (int j = 0; j < 64; ++j) h2[j] = s_b2[j];
    #pragma unroll
    for (int k = 0; k < 64; ++k) {
        const float hv = h1[k];
        #pragma unroll
        for (int j = 0; j < 64; ++j) h2[j] = fmaf(hv, s_w2[k * 64 + j], h2[j]);
    }
    #pragma unroll
    for (int j = 0; j < 64; ++j) h2[j] = fmaxf(h2[j], 0.f);
    float o0 = s_b3[0], o1 = s_b3[1], o2 = s_b3[2];
    #pragma unroll
    for (int j = 0; j < 64; ++j) {
        const float hv = h2[j];
        o0 = fmaf(hv, s_w3[j * 3 + 0], o0);
        o1 = fmaf(hv, s_w3[j * 3 + 1], o1);
        o2 = fmaf(hv, s_w3[j * 3 + 2], o2);
    }
    out[3 * i + 0] = 1.f / (1.f + __expf(-o0));
    out[3 * i + 1] = 1.f / (1.f + __expf(-o1));
    out[3 * i + 2] = 1.f / (1.f + __expf(-o2));
}

// encode variant for the fp16 fallback path
__global__ __launch_bounds__(256, 8)
void ingp_encode_h2(const float* __restrict__ x,
                    const float* __restrict__ table,
                    __half2* __restrict__ feat16, int n, ResArr res)
{
    const int i = blockIdx.x * 256 + threadIdx.x;
    const int l = blockIdx.y;
    if (i >= n) return;
    const float xx = x[3 * i + 0], xy = x[3 * i + 1], xz = x[3 * i + 2];
    const float rm1 = res.v[l];
    const float px = xx * rm1, py = xy * rm1, pz = xz * rm1;
    const float fpx = floorf(px), fpy = floorf(py), fpz = floorf(pz);
    const float fx = px - fpx, fy = py - fpy, fz = pz - fpz;
    const uint32_t ix = (uint32_t)fpx, iy = (uint32_t)fpy, iz = (uint32_t)fpz;
    const uint32_t hy0 = iy * PRIME1, hy1 = (iy + 1u) * PRIME1;
    const uint32_t hz0 = iz * PRIME2, hz1 = (iz + 1u) * PRIME2;
    const float* tl = table + (size_t)l * (size_t)TSIZE * 2u;
    float a0 = 0.f, a1 = 0.f;
    #pragma unroll
    for (int c = 0; c < 8; ++c) {
        const int bi = (c >> 2) & 1, bj = (c >> 1) & 1, bk = c & 1;
        const uint32_t h = ((ix + (uint32_t)bi) ^ (bj ? hy1 : hy0) ^ (bk ? hz1 : hz0)) & TMASK;
        const float2 tv = *reinterpret_cast<const float2*>(tl + (size_t)h * 2u);
        const float w = (bi ? fx : 1.f - fx) * (bj ? fy : 1.f - fy) * (bk ? fz : 1.f - fz);
        a0 = fmaf(w, tv.x, a0);
        a1 = fmaf(w, tv.y, a1);
    }
    feat16[(size_t)l * n + i] = __floats2half2_rn(a0, a1);
}

extern "C" void kernel_launch(void* const* d_in, const int* in_sizes, int n_in,
                              void* d_out, int out_size, void* d_ws, size_t ws_size,
                              hipStream_t stream)
{
    const float* x     = (const float*)d_in[0];
    const float* table = (const float*)d_in[1];
    const float* w1    = (const float*)d_in[2];
    const float* b1    = (const float*)d_in[3];
    const float* w2    = (const float*)d_in[4];
    const float* b2    = (const float*)d_in[5];
    const float* w3    = (const float*)d_in[6];
    const float* b3    = (const float*)d_in[7];
    float* out = (float*)d_out;

    const int n = in_sizes[0] / 3;

    ResArr res;
    const double S = (double)1.3819061f;
    double p = 1.0;
    for (int l = 0; l < LVLS; ++l) {
        res.v[l] = (float)floor(16.0 * p) - 1.0f;
        p *= S;
    }

    const int gb = (n + 255) / 256;
    const size_t feat_bytes = (size_t)LVLS * (size_t)n * 4u;        // 32 MB
    const size_t need_mfma  = 16384 + feat_bytes;

    if (ws_size >= need_mfma) {
        ushort* w1t = (ushort*)d_ws;           // 2048 elems
        ushort* w2t = w1t + 2048;              // 4096 elems
        ushort* w3t = w2t + 4096;              // 1024 elems
        uint*   feat = (uint*)((char*)d_ws + 16384);
        ingp_prep<<<28, 256, 0, stream>>>(w1, w2, w3, w1t, w2t, w3t);
        dim3 gridA(gb, LVLS);
        ingp_encode<<<gridA, 256, 0, stream>>>(x, table, feat, n, res);
        ingp_mlp_mfma<<<gb, 256, 0, stream>>>(feat, w1t, w2t, w3t,
                                              b1, b2, b3, out, n);
    } else {
        dim3 gridA(gb, LVLS);
        ingp_encode_h2<<<gridA, 256, 0, stream>>>(x, table, (__half2*)d_ws, n, res);
        ingp_mlp<<<gb, 256, 0, stream>>>((const __half2*)d_ws,
                                         w1, b1, w2, b2, w3, b3, out, n);
    }
}

// Round 5
// 179.482 us; speedup vs baseline: 3.1695x; 1.1244x over previous
//
#include <hip/hip_runtime.h>
#include <hip/hip_fp16.h>
#include <math.h>

// Instant-NGP forward:
//   conv:   table f32 -> fp16-pair table (4B/entry) in ws; x -> float4 pack.
//   encode: one thread per (point, level). dim0 hash prime == 1 =>
//           corner pair distance d = ix^(ix+1) in {1,3} for 75% of ix;
//           fp16 entries put the whole pair inside one aligned 16B block
//           -> 4 uint4 loads instead of 8 gathers.
//   mlp:    MFMA bf16 16x16x32; 4 waves/block, 64 points/wave.

constexpr int      LVLS   = 16;
constexpr uint32_t TSIZE  = 1u << 19;
constexpr uint32_t TMASK  = TSIZE - 1u;
constexpr uint32_t PRIME1 = 2654435761u;
constexpr uint32_t PRIME2 = 805459861u;

struct ResArr { float v[LVLS]; };  // res[l] - 1.0f

typedef __attribute__((ext_vector_type(8))) short short8v;  // 8 bf16 (4 VGPRs)
typedef __attribute__((ext_vector_type(4))) float float4v;  // MFMA 16x16 acc

__device__ inline ushort f2bf(float f) {          // RNE f32 -> bf16
    uint u = __float_as_uint(f);
    u += 0x7fffu + ((u >> 16) & 1u);
    return (ushort)(u >> 16);
}

__device__ inline float2 h2f(uint u) {
    __half2 h = *reinterpret_cast<__half2*>(&u);
    return __half22float2(h);
}

__device__ inline uint pick4(const uint4& b, uint j) {
    const uint lo = (j & 1u) ? b.y : b.x;
    const uint hi = (j & 1u) ? b.w : b.z;
    return (j & 2u) ? hi : lo;
}

// ---------------- conv: table -> fp16 pairs; x -> float4 ----------------
__global__ __launch_bounds__(256)
void ingp_conv(const float* __restrict__ table, uint* __restrict__ tab16,
               const float* __restrict__ x, float4* __restrict__ x4, int n)
{
    const int t = blockIdx.x * 256 + threadIdx.x;
    const int HALF = LVLS * (int)TSIZE / 2;      // entry pairs handled per thread
    if (t < HALF) {
        const float4 v = *reinterpret_cast<const float4*>(table + (size_t)t * 4u);
        __half2 ha = __floats2half2_rn(v.x, v.y);
        __half2 hb = __floats2half2_rn(v.z, v.w);
        uint2 o;
        o.x = *reinterpret_cast<uint*>(&ha);
        o.y = *reinterpret_cast<uint*>(&hb);
        *reinterpret_cast<uint2*>(tab16 + (size_t)t * 2u) = o;
    }
    if (t < n)
        x4[t] = make_float4(x[3 * t + 0], x[3 * t + 1], x[3 * t + 2], 0.f);
}

// ---------------- prep: weight transpose + bf16 cast ----------------
__global__ __launch_bounds__(256)
void ingp_prep(const float* __restrict__ w1, const float* __restrict__ w2,
               const float* __restrict__ w3,
               ushort* __restrict__ w1t, ushort* __restrict__ w2t,
               ushort* __restrict__ w3t)
{
    const int t = blockIdx.x * 256 + threadIdx.x;
    if (t < 2048) {                       // w1t[n*32+k] = w1[k*64+n]
        const int nn = t >> 5, k = t & 31;
        w1t[t] = f2bf(w1[k * 64 + nn]);
    } else if (t < 2048 + 4096) {         // w2t[n*64+k] = w2[k*64+n]
        const int q = t - 2048;
        const int nn = q >> 6, k = q & 63;
        w2t[q] = f2bf(w2[k * 64 + nn]);
    } else if (t < 2048 + 4096 + 1024) {  // w3t padded to [16][64]
        const int q = t - 6144;
        const int nn = q >> 6, k = q & 63;
        w3t[q] = (nn < 3) ? f2bf(w3[k * 3 + nn]) : (ushort)0;
    }
}

// ---------------- Kernel A: encode (fp16 table, block-pair loads) ---------
__global__ __launch_bounds__(256, 8)
void ingp_encode_f16(const float4* __restrict__ x4,
                     const uint* __restrict__ tab16,
                     uint* __restrict__ feat, int n, ResArr res)
{
    const int i = blockIdx.x * 256 + threadIdx.x;
    const int l = blockIdx.y;
    if (i >= n) return;

    const float4 xp = x4[i];
    const float rm1 = res.v[l];
    const float px = xp.x * rm1, py = xp.y * rm1, pz = xp.z * rm1;
    const float fpx = floorf(px), fpy = floorf(py), fpz = floorf(pz);
    const float fx = px - fpx, fy = py - fpy, fz = pz - fpz;
    const uint32_t ix = (uint32_t)fpx;
    const uint32_t iy = (uint32_t)fpy;
    const uint32_t iz = (uint32_t)fpz;
    const uint32_t hy0 = iy * PRIME1, hy1 = (iy + 1u) * PRIME1;
    const uint32_t hz0 = iz * PRIME2, hz1 = (iz + 1u) * PRIME2;
    const uint* tl = tab16 + (size_t)l * (size_t)TSIZE;

    uint32_t h0[4], h1[4];
    #pragma unroll
    for (int p = 0; p < 4; ++p) {
        const uint32_t bj = (p >> 1) & 1, bk = p & 1;
        const uint32_t hyz = (bj ? hy1 : hy0) ^ (bk ? hz1 : hz0);
        h0[p] = (ix ^ hyz) & TMASK;
        h1[p] = ((ix + 1u) ^ hyz) & TMASK;
    }

    uint e0[4], e1[4];
    if ((ix & 3u) != 3u) {
        // pair distance d = ix^(ix+1) is 1 or 3 -> both corners inside one
        // aligned 4-entry (16B) block.
        #pragma unroll
        for (int p = 0; p < 4; ++p) {
            const uint32_t base = h0[p] & ~3u;
            const uint4 blk = *reinterpret_cast<const uint4*>(tl + base);
            e0[p] = pick4(blk, h0[p] & 3u);
            e1[p] = pick4(blk, h1[p] & 3u);
        }
    } else {
        #pragma unroll
        for (int p = 0; p < 4; ++p) {
            e0[p] = tl[h0[p]];
            e1[p] = tl[h1[p]];
        }
    }

    const float gx0 = 1.f - fx, gx1 = fx;
    float a0 = 0.f, a1 = 0.f;
    #pragma unroll
    for (int p = 0; p < 4; ++p) {
        const int bj = (p >> 1) & 1, bk = p & 1;
        const float wyz = (bj ? fy : 1.f - fy) * (bk ? fz : 1.f - fz);
        const float w0 = wyz * gx0, w1 = wyz * gx1;
        const float2 c0 = h2f(e0[p]);
        const float2 c1 = h2f(e1[p]);
        a0 = fmaf(w0, c0.x, a0);
        a1 = fmaf(w0, c0.y, a1);
        a0 = fmaf(w1, c1.x, a0);
        a1 = fmaf(w1, c1.y, a1);
    }
    feat[(size_t)l * n + i] = (uint)f2bf(a0) | ((uint)f2bf(a1) << 16);
}

// ---------------- mid fallback: f32 table, paired-corner loads ------------
__global__ __launch_bounds__(256, 8)
void ingp_encode(const float* __restrict__ x,
                 const float* __restrict__ table,
                 uint* __restrict__ feat, int n, ResArr res)
{
    const int i = blockIdx.x * 256 + threadIdx.x;
    const int l = blockIdx.y;
    if (i >= n) return;
    const float xx = x[3 * i + 0], xy = x[3 * i + 1], xz = x[3 * i + 2];
    const float rm1 = res.v[l];
    const float px = xx * rm1, py = xy * rm1, pz = xz * rm1;
    const float fpx = floorf(px), fpy = floorf(py), fpz = floorf(pz);
    const float fx = px - fpx, fy = py - fpy, fz = pz - fpz;
    const uint32_t ix = (uint32_t)fpx, iy = (uint32_t)fpy, iz = (uint32_t)fpz;
    const uint32_t hy0 = iy * PRIME1, hy1 = (iy + 1u) * PRIME1;
    const uint32_t hz0 = iz * PRIME2, hz1 = (iz + 1u) * PRIME2;
    const float* tl = table + (size_t)l * (size_t)TSIZE * 2u;

    uint32_t idx0[4], idx1[4];
    #pragma unroll
    for (int p = 0; p < 4; ++p) {
        const uint32_t bj = (p >> 1) & 1, bk = p & 1;
        const uint32_t hyz = (bj ? hy1 : hy0) ^ (bk ? hz1 : hz0);
        idx0[p] = (ix ^ hyz) & TMASK;
        idx1[p] = ((ix + 1u) ^ hyz) & TMASK;
    }
    float2 c0[4], c1[4];
    if ((ix & 1u) == 0u) {
        #pragma unroll
        for (int p = 0; p < 4; ++p) {
            const uint32_t base = idx0[p] & ~1u;
            const float4 q = *reinterpret_cast<const float4*>(tl + (size_t)base * 2u);
            if (idx0[p] & 1u) { c0[p] = make_float2(q.z, q.w); c1[p] = make_float2(q.x, q.y); }
            else              { c0[p] = make_float2(q.x, q.y); c1[p] = make_float2(q.z, q.w); }
        }
    } else {
        #pragma unroll
        for (int p = 0; p < 4; ++p) {
            c0[p] = *reinterpret_cast<const float2*>(tl + (size_t)idx0[p] * 2u);
            c1[p] = *reinterpret_cast<const float2*>(tl + (size_t)idx1[p] * 2u);
        }
    }
    const float gx0 = 1.f - fx, gx1 = fx;
    float a0 = 0.f, a1 = 0.f;
    #pragma unroll
    for (int p = 0; p < 4; ++p) {
        const int bj = (p >> 1) & 1, bk = p & 1;
        const float wyz = (bj ? fy : 1.f - fy) * (bk ? fz : 1.f - fz);
        const float w0 = wyz * gx0, w1 = wyz * gx1;
        a0 = fmaf(w0, c0[p].x, a0);
        a1 = fmaf(w0, c0[p].y, a1);
        a0 = fmaf(w1, c1[p].x, a0);
        a1 = fmaf(w1, c1[p].y, a1);
    }
    feat[(size_t)l * n + i] = (uint)f2bf(a0) | ((uint)f2bf(a1) << 16);
}

// ---------------- Kernel B: MFMA MLP ----------------
__global__ __launch_bounds__(256)
void ingp_mlp_mfma(const uint* __restrict__ feat,
                   const ushort* __restrict__ w1t,
                   const ushort* __restrict__ w2t,
                   const ushort* __restrict__ w3t,
                   const float* __restrict__ b1,
                   const float* __restrict__ b2,
                   const float* __restrict__ b3,
                   float* __restrict__ out, int n)
{
    __shared__ ushort s_h[4][64][72];   // per-wave transpose tile, padded (+8)
    const int tid = threadIdx.x;
    const int wv = tid >> 6;
    const int ln = tid & 63;
    const int lm = ln & 15;
    const int lk = ln >> 4;
    const int base = blockIdx.x * 256 + wv * 64;

    short8v a1[4];
    #pragma unroll
    for (int mt = 0; mt < 4; ++mt) {
        int pt = base + mt * 16 + lm;
        pt = pt < n ? pt : (n - 1);
        union { uint u[4]; short8v v; } c;
        #pragma unroll
        for (int j = 0; j < 4; ++j)
            c.u[j] = feat[(size_t)(lk * 4 + j) * (size_t)n + pt];
        a1[mt] = c.v;
    }

    float4v acc[4][4];
    #pragma unroll
    for (int nt = 0; nt < 4; ++nt) {
        const float bv = b1[nt * 16 + lm];
        #pragma unroll
        for (int mt = 0; mt < 4; ++mt)
            acc[mt][nt] = (float4v){bv, bv, bv, bv};
    }
    #pragma unroll
    for (int nt = 0; nt < 4; ++nt) {
        const short8v bfr = *(const short8v*)(w1t + (nt * 16 + lm) * 32 + lk * 8);
        #pragma unroll
        for (int mt = 0; mt < 4; ++mt)
            acc[mt][nt] = __builtin_amdgcn_mfma_f32_16x16x32_bf16(
                a1[mt], bfr, acc[mt][nt], 0, 0, 0);
    }
    #pragma unroll
    for (int mt = 0; mt < 4; ++mt)
        #pragma unroll
        for (int nt = 0; nt < 4; ++nt)
            #pragma unroll
            for (int r = 0; r < 4; ++r)
                s_h[wv][mt * 16 + lk * 4 + r][nt * 16 + lm] =
                    f2bf(fmaxf(acc[mt][nt][r], 0.f));
    __syncthreads();

    float4v acc2[4][4];
    #pragma unroll
    for (int nt = 0; nt < 4; ++nt) {
        const float bv = b2[nt * 16 + lm];
        #pragma unroll
        for (int mt = 0; mt < 4; ++mt)
            acc2[mt][nt] = (float4v){bv, bv, bv, bv};
    }
    #pragma unroll
    for (int ks = 0; ks < 2; ++ks) {
        short8v a2[4];
        #pragma unroll
        for (int mt = 0; mt < 4; ++mt)
            a2[mt] = *(const short8v*)&s_h[wv][mt * 16 + lm][ks * 32 + lk * 8];
        #pragma unroll
        for (int nt = 0; nt < 4; ++nt) {
            const short8v bfr =
                *(const short8v*)(w2t + (nt * 16 + lm) * 64 + ks * 32 + lk * 8);
            #pragma unroll
            for (int mt = 0; mt < 4; ++mt)
                acc2[mt][nt] = __builtin_amdgcn_mfma_f32_16x16x32_bf16(
                    a2[mt], bfr, acc2[mt][nt], 0, 0, 0);
        }
    }
    __syncthreads();
    #pragma unroll
    for (int mt = 0; mt < 4; ++mt)
        #pragma unroll
        for (int nt = 0; nt < 4; ++nt)
            #pragma unroll
            for (int r = 0; r < 4; ++r)
                s_h[wv][mt * 16 + lk * 4 + r][nt * 16 + lm] =
                    f2bf(fmaxf(acc2[mt][nt][r], 0.f));
    __syncthreads();

    float4v acc3[4];
    const float bv3 = (lm < 3) ? b3[lm] : 0.f;
    #pragma unroll
    for (int mt = 0; mt < 4; ++mt)
        acc3[mt] = (float4v){bv3, bv3, bv3, bv3};
    #pragma unroll
    for (int ks = 0; ks < 2; ++ks) {
        const short8v bfr = *(const short8v*)(w3t + lm * 64 + ks * 32 + lk * 8);
        #pragma unroll
        for (int mt = 0; mt < 4; ++mt) {
            const short8v a3 =
                *(const short8v*)&s_h[wv][mt * 16 + lm][ks * 32 + lk * 8];
            acc3[mt] = __builtin_amdgcn_mfma_f32_16x16x32_bf16(
                a3, bfr, acc3[mt], 0, 0, 0);
        }
    }
    if (lm < 3) {
        #pragma unroll
        for (int mt = 0; mt < 4; ++mt)
            #pragma unroll
            for (int r = 0; r < 4; ++r) {
                const int pt = base + mt * 16 + lk * 4 + r;
                if (pt < n)
                    out[pt * 3 + lm] = 1.f / (1.f + __expf(-acc3[mt][r]));
            }
    }
}

// ---------------- last fallback: f32 MLP + h2 encode ----------------
__global__ __launch_bounds__(256)
void ingp_mlp(const __half2* __restrict__ feat16,
              const float* __restrict__ w1, const float* __restrict__ b1,
              const float* __restrict__ w2, const float* __restrict__ b2,
              const float* __restrict__ w3, const float* __restrict__ b3,
              float* __restrict__ out, int n)
{
    __shared__ float s_w1[32 * 64];
    __shared__ float s_w2[64 * 64];
    __shared__ float s_w3[64 * 3];
    __shared__ float s_b1[64];
    __shared__ float s_b2[64];
    __shared__ float s_b3[3];
    for (int t = threadIdx.x; t < 32 * 64; t += 256) s_w1[t] = w1[t];
    for (int t = threadIdx.x; t < 64 * 64; t += 256) s_w2[t] = w2[t];
    for (int t = threadIdx.x; t < 64 * 3;  t += 256) s_w3[t] = w3[t];
    if (threadIdx.x < 64) { s_b1[threadIdx.x] = b1[threadIdx.x]; s_b2[threadIdx.x] = b2[threadIdx.x]; }
    if (threadIdx.x < 3) s_b3[threadIdx.x] = b3[threadIdx.x];
    __syncthreads();
    const int i = blockIdx.x * 256 + threadIdx.x;
    if (i >= n) return;
    float feat[32];
    #pragma unroll
    for (int l = 0; l < LVLS; ++l) {
        const float2 f = __half22float2(feat16[(size_t)l * n + i]);
        feat[2 * l + 0] = f.x;
        feat[2 * l + 1] = f.y;
    }
    float h1[64];
    #pragma unroll
    for (int j = 0; j < 64; ++j) h1[j] = s_b1[j];
    #pragma unroll
    for (int k = 0; k < 32; ++k) {
        const float fv = feat[k];
        #pragma unroll
        for (int j = 0; j < 64; ++j) h1[j] = fmaf(fv, s_w1[k * 64 + j], h1[j]);
    }
    #pragma unroll
    for (int j = 0; j < 64; ++j) h1[j] = fmaxf(h1[j], 0.f);
    float h2[64];
    #pragma unroll
    for (int j = 0; j < 64; ++j) h2[j] = s_b2[j];
    #pragma unroll
    for (int k = 0; k < 64; ++k) {
        const float hv = h1[k];
        #pragma unroll
        for (int j = 0; j < 64; ++j) h2[j] = fmaf(hv, s_w2[k * 64 + j], h2[j]);
    }
    #pragma unroll
    for (int j = 0; j < 64; ++j) h2[j] = fmaxf(h2[j], 0.f);
    float o0 = s_b3[0], o1 = s_b3[1], o2 = s_b3[2];
    #pragma unroll
    for (int j = 0; j < 64; ++j) {
        const float hv = h2[j];
        o0 = fmaf(hv, s_w3[j * 3 + 0], o0);
        o1 = fmaf(hv, s_w3[j * 3 + 1], o1);
        o2 = fmaf(hv, s_w3[j * 3 + 2], o2);
    }
    out[3 * i + 0] = 1.f / (1.f + __expf(-o0));
    out[3 * i + 1] = 1.f / (1.f + __expf(-o1));
    out[3 * i + 2] = 1.f / (1.f + __expf(-o2));
}

__global__ __launch_bounds__(256, 8)
void ingp_encode_h2(const float* __restrict__ x,
                    const float* __restrict__ table,
                    __half2* __restrict__ feat16, int n, ResArr res)
{
    const int i = blockIdx.x * 256 + threadIdx.x;
    const int l = blockIdx.y;
    if (i >= n) return;
    const float xx = x[3 * i + 0], xy = x[3 * i + 1], xz = x[3 * i + 2];
    const float rm1 = res.v[l];
    const float px = xx * rm1, py = xy * rm1, pz = xz * rm1;
    const float fpx = floorf(px), fpy = floorf(py), fpz = floorf(pz);
    const float fx = px - fpx, fy = py - fpy, fz = pz - fpz;
    const uint32_t ix = (uint32_t)fpx, iy = (uint32_t)fpy, iz = (uint32_t)fpz;
    const uint32_t hy0 = iy * PRIME1, hy1 = (iy + 1u) * PRIME1;
    const uint32_t hz0 = iz * PRIME2, hz1 = (iz + 1u) * PRIME2;
    const float* tl = table + (size_t)l * (size_t)TSIZE * 2u;
    float a0 = 0.f, a1 = 0.f;
    #pragma unroll
    for (int c = 0; c < 8; ++c) {
        const int bi = (c >> 2) & 1, bj = (c >> 1) & 1, bk = c & 1;
        const uint32_t h = ((ix + (uint32_t)bi) ^ (bj ? hy1 : hy0) ^ (bk ? hz1 : hz0)) & TMASK;
        const float2 tv = *reinterpret_cast<const float2*>(tl + (size_t)h * 2u);
        const float w = (bi ? fx : 1.f - fx) * (bj ? fy : 1.f - fy) * (bk ? fz : 1.f - fz);
        a0 = fmaf(w, tv.x, a0);
        a1 = fmaf(w, tv.y, a1);
    }
    feat16[(size_t)l * n + i] = __floats2half2_rn(a0, a1);
}

extern "C" void kernel_launch(void* const* d_in, const int* in_sizes, int n_in,
                              void* d_out, int out_size, void* d_ws, size_t ws_size,
                              hipStream_t stream)
{
    const float* x     = (const float*)d_in[0];
    const float* table = (const float*)d_in[1];
    const float* w1    = (const float*)d_in[2];
    const float* b1    = (const float*)d_in[3];
    const float* w2    = (const float*)d_in[4];
    const float* b2    = (const float*)d_in[5];
    const float* w3    = (const float*)d_in[6];
    const float* b3    = (const float*)d_in[7];
    float* out = (float*)d_out;

    const int n = in_sizes[0] / 3;

    ResArr res;
    const double S = (double)1.3819061f;
    double p = 1.0;
    for (int l = 0; l < LVLS; ++l) {
        res.v[l] = (float)floor(16.0 * p) - 1.0f;
        p *= S;
    }

    const int gb = (n + 255) / 256;
    const size_t feat_bytes = (size_t)LVLS * (size_t)n * 4u;               // 32 MB
    const size_t tab16_bytes = (size_t)LVLS * (size_t)TSIZE * 4u;          // 33.5 MB
    const size_t x4_bytes   = (size_t)n * 16u;                             // 8 MB

    const size_t off_tab16 = 16384;
    const size_t off_feat  = off_tab16 + tab16_bytes;
    const size_t off_x4    = off_feat + feat_bytes;
    const size_t need_full = off_x4 + x4_bytes;
    const size_t need_mid  = 16384 + feat_bytes;

    if (ws_size >= need_full) {
        ushort* w1t  = (ushort*)d_ws;
        ushort* w2t  = w1t + 2048;
        ushort* w3t  = w2t + 4096;
        uint*   tab16 = (uint*)((char*)d_ws + off_tab16);
        uint*   feat  = (uint*)((char*)d_ws + off_feat);
        float4* x4    = (float4*)((char*)d_ws + off_x4);

        const int conv_threads = LVLS * (int)TSIZE / 2;    // 4.19M
        ingp_conv<<<(conv_threads + 255) / 256, 256, 0, stream>>>(
            table, tab16, x, x4, n);
        ingp_prep<<<28, 256, 0, stream>>>(w1, w2, w3, w1t, w2t, w3t);
        dim3 gridA(gb, LVLS);
        ingp_encode_f16<<<gridA, 256, 0, stream>>>(x4, tab16, feat, n, res);
        ingp_mlp_mfma<<<gb, 256, 0, stream>>>(feat, w1t, w2t, w3t,
                                              b1, b2, b3, out, n);
    } else if (ws_size >= need_mid) {
        ushort* w1t = (ushort*)d_ws;
        ushort* w2t = w1t + 2048;
        ushort* w3t = w2t + 4096;
        uint*   feat = (uint*)((char*)d_ws + 16384);
        ingp_prep<<<28, 256, 0, stream>>>(w1, w2, w3, w1t, w2t, w3t);
        dim3 gridA(gb, LVLS);
        ingp_encode<<<gridA, 256, 0, stream>>>(x, table, feat, n, res);
        ingp_mlp_mfma<<<gb, 256, 0, stream>>>(feat, w1t, w2t, w3t,
                                              b1, b2, b3, out, n);
    } else {
        dim3 gridA(gb, LVLS);
        ingp_encode_h2<<<gridA, 256, 0, stream>>>(x, table, (__half2*)d_ws, n, res);
        ingp_mlp<<<gb, 256, 0, stream>>>((const __half2*)d_ws,
                                         w1, b1, w2, b2, w3, b3, out, n);
    }
}